// Round 12
// baseline (241.077 us; speedup 1.0000x reference)
//
#include <hip/hip_runtime.h>
#include <hip/hip_bf16.h>

typedef __hip_bfloat16 bf16;

#define HW 4096

typedef short s8v __attribute__((ext_vector_type(8)));
typedef short s4v __attribute__((ext_vector_type(4)));
typedef float f32x4 __attribute__((ext_vector_type(4)));
typedef _Float16 h8v __attribute__((ext_vector_type(8)));
typedef _Float16 h4v __attribute__((ext_vector_type(4)));

typedef __attribute__((address_space(3))) void lds_void;
typedef const __attribute__((address_space(1))) void g_void;

__device__ __forceinline__ float b2f(bf16 x) { return __bfloat162float(x); }
__device__ __forceinline__ bf16 f2b(float x) { return __float2bfloat16(x); }

__device__ __forceinline__ unsigned short f2bs(float f) {
  bf16 h = __float2bfloat16(f);
  unsigned short s;
  __builtin_memcpy(&s, &h, 2);
  return s;
}
__device__ __forceinline__ float s2f(short s) {
  return __uint_as_float(((unsigned)(unsigned short)s) << 16);
}
__device__ __forceinline__ short h2s(_Float16 h) {
  short s;
  __builtin_memcpy(&s, &h, 2);
  return s;
}
// packed bf16-pair decode: element at lower address = low 16 bits
__device__ __forceinline__ float blo(unsigned u) { return __uint_as_float(u << 16); }
__device__ __forceinline__ float bhi(unsigned u) {
  return __uint_as_float(u & 0xffff0000u);
}

__device__ __forceinline__ void stv(float* p, float v) { *p = v; }
__device__ __forceinline__ void stv(bf16* p, float v) { *p = f2b(v); }

// ---------------------------------------------------------------------------
// Transpose + split: x [b][256][HW] f32 -> hi/lo [b][HW][256] f16.
// Extra grid slice (blockIdx.y == 4): fp32 -> (hi,lo) split of w_qkv.
// ---------------------------------------------------------------------------
__global__ __launch_bounds__(256) void transpose_split_kernel(
    const float* __restrict__ In, _Float16* __restrict__ Hi,
    _Float16* __restrict__ Lo, const float* __restrict__ W,
    _Float16* __restrict__ WHi, _Float16* __restrict__ WLo) {
  if (blockIdx.y == 4) {  // weight-conversion slice
    int id = blockIdx.z * 64 + blockIdx.x;
    if (id < 192) {
      int i = id * 256 + threadIdx.x;  // i < 49152 = 768*256/4
      f32x4 v = *(const f32x4*)(W + (size_t)i * 4);
      h4v h, l;
#pragma unroll
      for (int q = 0; q < 4; ++q) {
        _Float16 hi = (_Float16)v[q];
        h[q] = hi;
        l[q] = (_Float16)(v[q] - (float)hi);
      }
      *(h4v*)(WHi + (size_t)i * 4) = h;
      *(h4v*)(WLo + (size_t)i * 4) = l;
    }
    return;
  }
  __shared__ _Float16 sH[64][68];
  __shared__ _Float16 sL[64][68];
  const int b = blockIdx.z;
  const int n0 = blockIdx.x * 64, c0 = blockIdx.y * 64;
  const int tl = threadIdx.x & 15, tr = threadIdx.x >> 4;
  const float* Ib = In + ((size_t)b * 256 + c0) * HW + n0;
#pragma unroll
  for (int i = 0; i < 4; ++i) {
    int cc = tr + i * 16;
    f32x4 v = *(const f32x4*)(Ib + (size_t)cc * HW + tl * 4);
#pragma unroll
    for (int q = 0; q < 4; ++q) {
      _Float16 hi = (_Float16)v[q];
      sH[cc][tl * 4 + q] = hi;
      sL[cc][tl * 4 + q] = (_Float16)(v[q] - (float)hi);
    }
  }
  __syncthreads();
  size_t obase = ((size_t)b * HW + n0) * 256 + c0;
#pragma unroll
  for (int i = 0; i < 4; ++i) {
    int nn = tr + i * 16;
    h4v h, l;
#pragma unroll
    for (int q = 0; q < 4; ++q) {
      h[q] = sH[tl * 4 + q][nn];
      l[q] = sL[tl * 4 + q][nn];
    }
    *(h4v*)(Hi + obase + (size_t)nn * 256 + tl * 4) = h;
    *(h4v*)(Lo + obase + (size_t)nn * 256 + tl * 4) = l;
  }
}

// ---------------------------------------------------------------------------
// fp32 -> fp16 plain conversion for w_proj (after attn, into dead pw region).
// ---------------------------------------------------------------------------
__global__ __launch_bounds__(256) void cvt_f16_kernel(
    const float* __restrict__ W, _Float16* __restrict__ Hi, int n4) {
  int i = blockIdx.x * 256 + threadIdx.x;
  if (i >= n4) return;
  f32x4 v = *(const f32x4*)(W + (size_t)i * 4);
  h4v h;
#pragma unroll
  for (int q = 0; q < 4; ++q) h[q] = (_Float16)v[q];
  *(h4v*)(Hi + (size_t)i * 4) = h;
}

// ---------------------------------------------------------------------------
// GEMM1 dedicated kernel — r8 codegen shape (45.0-45.2 µs measured):
// 128x128 tile, 256 threads = 4 waves (2x2), 3-plane split-fp16,
// single-buffer, inline staging loops.
// ---------------------------------------------------------------------------
__global__ __launch_bounds__(256) void mfma_gemm1_kernel(
    const _Float16* __restrict__ A,   // [2][768][256] planes (hi, lo)
    const _Float16* __restrict__ Bt,  // [2][8][HW][256] planes (hi, lo)
    bf16* __restrict__ Out) {         // [8][768][HW]
  constexpr int M = 768, K = 256;
  __shared__ __align__(16) _Float16 sA[2][128 * 32];
  __shared__ __align__(16) _Float16 sB[2][128 * 32];
  const int b = blockIdx.z;
  const int ob = blockIdx.y * 128;
  const int nb = blockIdx.x * 128;
  const int tid = threadIdx.x;
  const int lane = tid & 63;
  const int wave = tid >> 6;
  const int wm = (wave >> 1) * 64;
  const int wn = (wave & 1) * 64;
  const int lr = lane & 15;
  const int kg = lane >> 4;

  f32x4 acc[4][4] = {};

  for (int k0 = 0; k0 < K; k0 += 32) {
#pragma unroll
    for (int p = 0; p < 2; ++p) {
      const _Float16* Ab = A + (size_t)p * M * K + (size_t)ob * K + k0;
#pragma unroll
      for (int t = 0; t < 2; ++t) {
        int c = t * 256 + tid;
        int row = c >> 2, col = c & 3;
        int kc = col ^ ((row >> 1) & 3);
        __builtin_amdgcn_global_load_lds(
            (g_void*)(Ab + (size_t)row * K + kc * 8),
            (lds_void*)(sA[p] + (size_t)(t * 256 + (tid & ~63)) * 8), 16, 0, 0);
      }
    }
#pragma unroll
    for (int q = 0; q < 2; ++q) {
      const _Float16* Bb =
          Bt + (size_t)q * 8 * HW * K + ((size_t)b * HW + nb) * K + k0;
#pragma unroll
      for (int t = 0; t < 2; ++t) {
        int c = t * 256 + tid;
        int row = c >> 2, col = c & 3;
        int kc = col ^ ((row >> 1) & 3);
        __builtin_amdgcn_global_load_lds(
            (g_void*)(Bb + (size_t)row * K + kc * 8),
            (lds_void*)(sB[q] + (size_t)(t * 256 + (tid & ~63)) * 8), 16, 0, 0);
      }
    }
    __syncthreads();

    h8v af[2][4], bf_[2][4];
#pragma unroll
    for (int p = 0; p < 2; ++p)
#pragma unroll
      for (int i = 0; i < 4; ++i) {
        int r = wm + i * 16 + lr;
        af[p][i] = *(const h8v*)(sA[p] + (size_t)r * 32 + (kg ^ ((r >> 1) & 3)) * 8);
      }
#pragma unroll
    for (int q = 0; q < 2; ++q)
#pragma unroll
      for (int j = 0; j < 4; ++j) {
        int r = wn + j * 16 + lr;
        bf_[q][j] = *(const h8v*)(sB[q] + (size_t)r * 32 + (kg ^ ((r >> 1) & 3)) * 8);
      }

#pragma unroll
    for (int i = 0; i < 4; ++i)
#pragma unroll
      for (int j = 0; j < 4; ++j) {
        acc[i][j] = __builtin_amdgcn_mfma_f32_16x16x32_f16(af[0][i], bf_[0][j],
                                                           acc[i][j], 0, 0, 0);
        acc[i][j] = __builtin_amdgcn_mfma_f32_16x16x32_f16(af[1][i], bf_[0][j],
                                                           acc[i][j], 0, 0, 0);
        acc[i][j] = __builtin_amdgcn_mfma_f32_16x16x32_f16(af[0][i], bf_[1][j],
                                                           acc[i][j], 0, 0, 0);
      }
    __syncthreads();
  }

  // epilogue: D row = (lane>>4)*4 + reg, col = lane&15  (m89-verified)
#pragma unroll
  for (int i = 0; i < 4; ++i) {
#pragma unroll
    for (int r = 0; r < 4; ++r) {
      int o = ob + wm + i * 16 + kg * 4 + r;
      bf16* orow = Out + ((size_t)b * M + o) * HW + nb + wn + lr;
#pragma unroll
      for (int j = 0; j < 4; ++j) stv(orow + j * 16, acc[i][j][r]);
    }
  }
}

// ---------------------------------------------------------------------------
// GEMM2: fp16 MFMA, double-buffered (unchanged from r9).
// ---------------------------------------------------------------------------
template <int M, int K, int BM, int AP, int BP, bool FUSE_BN, bool DBUF,
          typename TOUT>
__global__ __launch_bounds__(256) void mfma_gemm_f16(
    const _Float16* __restrict__ A,   // [AP][M][K] planes
    const _Float16* __restrict__ Bt,  // [BP][8][HW][K] planes
    TOUT* __restrict__ Out,           // [8][M][HW]
    const float* __restrict__ bng, const float* __restrict__ bnb,
    const float* __restrict__ bnm, const float* __restrict__ bnv) {
  constexpr int WMF = BM / 32;
  constexpr int NBUF = DBUF ? 2 : 1;
  __shared__ __align__(16) _Float16 sA[NBUF][AP][BM * 32];
  __shared__ __align__(16) _Float16 sB[NBUF][BP][128 * 32];
  const int b = blockIdx.z;
  const int ob = blockIdx.y * BM;
  const int nb = blockIdx.x * 128;
  const int tid = threadIdx.x;
  const int lane = tid & 63;
  const int wave = tid >> 6;
  const int wm = (wave >> 1) * (BM / 2);
  const int wn = (wave & 1) * 64;
  const int lr = lane & 15;
  const int kg = lane >> 4;

  f32x4 acc[WMF][4] = {};

  auto stage = [&](int buf, int k0) {
#pragma unroll
    for (int p = 0; p < AP; ++p) {
      const _Float16* Ab = A + (size_t)p * M * K + (size_t)ob * K + k0;
#pragma unroll
      for (int t = 0; t < BM / 64; ++t) {
        int c = t * 256 + tid;
        int row = c >> 2, col = c & 3;
        int kc = col ^ ((row >> 1) & 3);
        __builtin_amdgcn_global_load_lds(
            (g_void*)(Ab + (size_t)row * K + kc * 8),
            (lds_void*)(sA[buf][p] + (size_t)(t * 256 + (tid & ~63)) * 8), 16,
            0, 0);
      }
    }
#pragma unroll
    for (int q = 0; q < BP; ++q) {
      const _Float16* Bb =
          Bt + (size_t)q * 8 * HW * K + ((size_t)b * HW + nb) * K + k0;
#pragma unroll
      for (int t = 0; t < 2; ++t) {
        int c = t * 256 + tid;
        int row = c >> 2, col = c & 3;
        int kc = col ^ ((row >> 1) & 3);
        __builtin_amdgcn_global_load_lds(
            (g_void*)(Bb + (size_t)row * K + kc * 8),
            (lds_void*)(sB[buf][q] + (size_t)(t * 256 + (tid & ~63)) * 8), 16,
            0, 0);
      }
    }
  };

  auto compute = [&](int buf) {
    h8v af[AP][WMF], bf_[BP][4];
#pragma unroll
    for (int p = 0; p < AP; ++p)
#pragma unroll
      for (int i = 0; i < WMF; ++i) {
        int r = wm + i * 16 + lr;
        af[p][i] = *(const h8v*)(sA[buf][p] + (size_t)r * 32 +
                                 (kg ^ ((r >> 1) & 3)) * 8);
      }
#pragma unroll
    for (int q = 0; q < BP; ++q)
#pragma unroll
      for (int j = 0; j < 4; ++j) {
        int r = wn + j * 16 + lr;
        bf_[q][j] = *(const h8v*)(sB[buf][q] + (size_t)r * 32 +
                                  (kg ^ ((r >> 1) & 3)) * 8);
      }
#pragma unroll
    for (int i = 0; i < WMF; ++i)
#pragma unroll
      for (int j = 0; j < 4; ++j) {
        acc[i][j] = __builtin_amdgcn_mfma_f32_16x16x32_f16(af[0][i], bf_[0][j],
                                                           acc[i][j], 0, 0, 0);
        if (AP > 1)
          acc[i][j] = __builtin_amdgcn_mfma_f32_16x16x32_f16(
              af[1][i], bf_[0][j], acc[i][j], 0, 0, 0);
        if (BP > 1)
          acc[i][j] = __builtin_amdgcn_mfma_f32_16x16x32_f16(
              af[0][i], bf_[1][j], acc[i][j], 0, 0, 0);
      }
  };

  if (DBUF) {
    stage(0, 0);
    __syncthreads();
    int cur = 0;
#pragma unroll
    for (int k0 = 32; k0 < K; k0 += 32) {
      stage(cur ^ 1, k0);  // prefetch next tile (in flight during compute)
      compute(cur);
      __syncthreads();  // vmcnt drain: next buf ready, cur reusable
      cur ^= 1;
    }
    compute(cur);  // tail tile, no prefetch
  } else {
    for (int k0 = 0; k0 < K; k0 += 32) {
      stage(0, k0);
      __syncthreads();
      compute(0);
      __syncthreads();
    }
  }

  // epilogue: D row = (lane>>4)*4 + reg, col = lane&15  (m89-verified)
#pragma unroll
  for (int i = 0; i < WMF; ++i) {
#pragma unroll
    for (int r = 0; r < 4; ++r) {
      int o = ob + wm + i * 16 + kg * 4 + r;
      float scale = 1.f, shift = 0.f;
      if (FUSE_BN) {
        scale = bng[o] * rsqrtf(bnv[o] + 1e-5f);
        shift = bnb[o] - bnm[o] * scale;
      }
      TOUT* orow = Out + ((size_t)b * M + o) * HW + nb + wn + lr;
#pragma unroll
      for (int j = 0; j < 4; ++j) {
        float v = acc[i][j][r];
        if (FUSE_BN) v = v * scale + shift;
        stv(orow + j * 16, v);
      }
    }
  }
}

// ---------------------------------------------------------------------------
// Fused depthwise 5x5 + grouped pointwise — bf16 LDS tile. (unchanged)
// ---------------------------------------------------------------------------
__global__ __launch_bounds__(256) void dwpw_kernel(
    const bf16* __restrict__ qkv,   // [B, 768, HW]
    const float* __restrict__ wdw,  // [768, 25]
    const float* __restrict__ wpw,  // [96, 8, 8]
    bf16* __restrict__ pw) {        // [B, 768, HW]
  constexpr int PLANE = 1484;
  constexpr int ROW = 72;
  __shared__ __align__(16) short sQ[8 * PLANE];
  const int b = blockIdx.z;
  const int g = blockIdx.y;
  const int h0 = blockIdx.x * 16;
  const int tid = threadIdx.x;
  const bf16* qb = qkv + ((size_t)b * 768 + g * 8) * HW;

  if (tid < 160) {
    int ci = tid / 20, rr = tid % 20;
    *(int*)&sQ[ci * PLANE + rr * ROW + 0] = 0;
    *(int*)&sQ[ci * PLANE + rr * ROW + 66] = 0;
  }

#pragma unroll
  for (int i = 0; i < 5; ++i) {
    int slot = tid + i * 256;
    int ci = slot & 7;
    int seg = (slot >> 3) & 7;
    int rr = slot >> 6;
    int h = h0 + rr - 2;
    int w4[4] = {0, 0, 0, 0};
    if (h >= 0 && h < 64) {
      s8v raw = *(const s8v*)(qb + (size_t)ci * HW + h * 64 + seg * 8);
      __builtin_memcpy(w4, &raw, 16);
    }
    short* dst = &sQ[ci * PLANE + rr * ROW + 2 + seg * 8];
#pragma unroll
    for (int q = 0; q < 4; ++q) ((int*)dst)[q] = w4[q];
  }
  __syncthreads();

  const int r = tid >> 4;
  const int c4 = (tid & 15) * 4;

  float accdw[8][4] = {};
#pragma unroll
  for (int ci = 0; ci < 8; ++ci) {
    const short* rowb = &sQ[ci * PLANE + r * ROW + c4];
#pragma unroll
    for (int dy = 0; dy < 5; ++dy) {
      uint2 ua = *(const uint2*)(rowb + dy * ROW);
      uint2 ub = *(const uint2*)(rowb + dy * ROW + 4);
      float win[8] = {blo(ua.x), bhi(ua.x), blo(ua.y), bhi(ua.y),
                      blo(ub.x), bhi(ub.x), blo(ub.y), bhi(ub.y)};
#pragma unroll
      for (int dx = 0; dx < 5; ++dx) {
        float wv = wdw[(g * 8 + ci) * 25 + dy * 5 + dx];
#pragma unroll
        for (int j = 0; j < 4; ++j)
          accdw[ci][j] = fmaf(wv, win[j + dx], accdw[ci][j]);
      }
    }
  }

  bf16* obase = pw + ((size_t)b * 768 + g * 8) * HW + (h0 + r) * 64 + c4;
#pragma unroll
  for (int o = 0; o < 8; ++o) {
    float a[4] = {};
#pragma unroll
    for (int i = 0; i < 8; ++i) {
      float wv = wpw[g * 64 + o * 8 + i];
#pragma unroll
      for (int j = 0; j < 4; ++j) a[j] = fmaf(wv, accdw[i][j], a[j]);
    }
    s4v res;
#pragma unroll
    for (int j = 0; j < 4; ++j) res[j] = (short)f2bs(a[j]);
    *(s4v*)(obase + (size_t)o * HW) = res;
  }
}

// ---------------------------------------------------------------------------
// ReLU linear attention — single kernel, MFMA kv + FUSED TRANSPOSED OUTPUT:
// writes att_t[b][n][512] f16 directly (per pixel, this head's 8 channels
// are 16 contiguous bytes -> one 16-B store). Eliminates the separate
// 64-MiB att->att_t transpose pass. NOTE: att_t must NOT alias pw/qkv
// (attn reads both); it lives in the old att region (xt planes, dead).
// ---------------------------------------------------------------------------
__global__ __launch_bounds__(256) void attn_kernel(
    const bf16* __restrict__ qkv,    // [B, 768, HW]
    const bf16* __restrict__ pw,     // [B, 768, HW]
    _Float16* __restrict__ att_t) {  // [B, HW, 512] f16
  const int bh = blockIdx.x;
  const int b = bh >> 6, h = bh & 63;
  const bf16* src = (h < 32) ? qkv + ((size_t)b * 768 + 24 * h) * HW
                             : pw + ((size_t)b * 768 + 24 * h - 768) * HW;
  const int tid = threadIdx.x;
  const int lane = tid & 63, wave = tid >> 6;
  const int fr = lane & 15;  // A-row / B-col index
  const int kg = lane >> 4;  // k-slot group (8 px each)

  const bf16* Kbase = src + (size_t)8 * HW;
  const bf16* Vbase = src + (size_t)16 * HW;
  const bool isK = fr < 8;

  s8v ones;
#pragma unroll
  for (int q = 0; q < 8; ++q) ones[q] = (short)0x3F80;  // bf16 1.0

  f32x4 acc[4] = {};
#pragma unroll
  for (int step = 0; step < 32; ++step) {
    const int px = wave * 1024 + step * 32 + kg * 8;
    s8v a = {};
    s8v bv = {};
    if (isK) {
      a = *(const s8v*)(Kbase + (size_t)fr * HW + px);
      unsigned au[4];
      __builtin_memcpy(au, &a, 16);
#pragma unroll
      for (int q = 0; q < 4; ++q) {
        unsigned s = (au[q] & 0x80008000u) >> 15;
        au[q] &= ~((s << 16) - s);
      }
      __builtin_memcpy(&a, au, 16);
      bv = *(const s8v*)(Vbase + (size_t)fr * HW + px);
    } else if (fr == 8) {
      bv = ones;
    }
    acc[step & 3] =
        __builtin_amdgcn_mfma_f32_16x16x32_bf16(a, bv, acc[step & 3], 0, 0, 0);
  }
  f32x4 accs = (acc[0] + acc[1]) + (acc[2] + acc[3]);

  __shared__ float sAcc[4][64][4];
  __shared__ float sKV[72];
#pragma unroll
  for (int q = 0; q < 4; ++q) sAcc[wave][lane][q] = accs[q];
  __syncthreads();
  if (wave == 0) {
#pragma unroll
    for (int q = 0; q < 4; ++q) {
      int r = kg * 4 + q;  // C row = d
      if (r < 8 && fr < 9) {
        sKV[r * 9 + fr] = sAcc[0][lane][q] + sAcc[1][lane][q] +
                          sAcc[2][lane][q] + sAcc[3][lane][q];
      }
    }
  }
  __syncthreads();
  float kvf[72];
#pragma unroll
  for (int t = 0; t < 72; ++t) kvf[t] = sKV[t];

  // q-pass: out = (q . kv) normalized; per pixel, write the head's 8
  // channels as ONE 16-B f16 store into att_t[b][n][h*8 .. h*8+7].
  _Float16* obase = att_t + (size_t)b * HW * 512 + h * 8;
  for (int n0 = tid * 8; n0 < HW; n0 += 2048) {
    s8v qvec[8];
#pragma unroll
    for (int d = 0; d < 8; ++d)
      qvec[d] = *(const s8v*)(src + (size_t)d * HW + n0);
#pragma unroll
    for (int p = 0; p < 8; ++p) {
      float qd[8];
#pragma unroll
      for (int d = 0; d < 8; ++d) qd[d] = fmaxf(s2f(qvec[d][p]), 0.f);
      float o[9] = {};
#pragma unroll
      for (int d = 0; d < 8; ++d)
#pragma unroll
        for (int e = 0; e < 9; ++e) o[e] = fmaf(qd[d], kvf[d * 9 + e], o[e]);
      float rinv = 1.0f / (o[8] + 1e-15f);
      h8v vals;
#pragma unroll
      for (int e = 0; e < 8; ++e) vals[e] = (_Float16)(o[e] * rinv);
      *(h8v*)(obase + (size_t)(n0 + p) * 512) = vals;
    }
  }
}

// ---------------------------------------------------------------------------
extern "C" void kernel_launch(void* const* d_in, const int* in_sizes, int n_in,
                              void* d_out, int out_size, void* d_ws, size_t ws_size,
                              hipStream_t stream) {
  const float* x = (const float*)d_in[0];       // [8,256,64,64]
  const float* w_qkv = (const float*)d_in[1];   // [768,256]
  const float* w_dw = (const float*)d_in[2];    // [768,1,5,5]
  const float* w_pw = (const float*)d_in[3];    // [96,8,8]
  const float* w_proj = (const float*)d_in[4];  // [256,512]
  const float* bng = (const float*)d_in[5];
  const float* bnb = (const float*)d_in[6];
  const float* bnm = (const float*)d_in[7];
  const float* bnv = (const float*)d_in[8];
  float* out = (float*)d_out;  // [8,256,64,64]

  // Workspace: 128 MiB, aliased by liveness.
  bf16* qkv = (bf16*)d_ws;                       // [8][768][HW]  48 MiB
  bf16* pw = qkv + (size_t)8 * 768 * HW;         // [8][768][HW]  48 MiB
  bf16* attreg = pw + (size_t)8 * 768 * HW;      // 32 MiB scratch region

  _Float16* xt_hi = (_Float16*)attreg;           // [8][HW][256] (dead after GEMM1)
  _Float16* xt_lo = xt_hi + (size_t)8 * HW * 256;
  _Float16* wq_hi = (_Float16*)pw;               // [768][256] x2 (pw dead until dwpw)
  _Float16* wq_lo = wq_hi + (size_t)768 * 256;
  _Float16* att_t = (_Float16*)attreg;           // [8][HW][512] f16 = 32 MiB exactly
                                                 //  (xt planes dead at attn time;
                                                 //   NOT pw/qkv — attn reads those)
  _Float16* wp_hi = (_Float16*)pw;               // [256][512] (pw dead after attn)

  // 0) transpose+split x; fused slice also split-converts w_qkv
  transpose_split_kernel<<<dim3(64, 5, 8), 256, 0, stream>>>(
      x, xt_hi, xt_lo, w_qkv, wq_hi, wq_lo);

  // 1) qkv = w_qkv @ x  (M=768, K=256) — r8-shape 128x128 inline kernel
  //    (3 planes REQUIRED: relu-boundary sign sensitivity in attention)
  mfma_gemm1_kernel<<<dim3(32, 6, 8), 256, 0, stream>>>(wq_hi, xt_hi, qkv);

  // 2) pw = grouped_pointwise(depthwise5x5(qkv))   (overwrites wq planes — dead)
  dwpw_kernel<<<dim3(4, 96, 8), 256, 0, stream>>>(qkv, w_dw, w_pw, pw);

  // 3) att_t = relu_linear_attention(concat(qkv, pw)) — fused transposed
  //    f16 output (overwrites xt planes — dead). No separate transpose pass.
  attn_kernel<<<dim3(512), 256, 0, stream>>>(qkv, pw, att_t);

  // 4) fp16-convert w_proj into dead pw region
  cvt_f16_kernel<<<dim3(128), 256, 0, stream>>>(w_proj, wp_hi, 256 * 512 / 4);

  // 5) out = BN(w_proj @ att)  (M=256, K=512) — plain fp16 MFMA, dbuf
  mfma_gemm_f16<256, 512, 64, 1, 1, true, true, float>
      <<<dim3(32, 4, 8), 256, 0, stream>>>(wp_hi, att_t, out, bng, bnb, bnm,
                                           bnv);
}

// Round 13
// 227.722 us; speedup vs baseline: 1.0586x; 1.0586x over previous
//
#include <hip/hip_runtime.h>
#include <hip/hip_bf16.h>

typedef __hip_bfloat16 bf16;

#define HW 4096

typedef short s8v __attribute__((ext_vector_type(8)));
typedef short s4v __attribute__((ext_vector_type(4)));
typedef float f32x4 __attribute__((ext_vector_type(4)));
typedef _Float16 h8v __attribute__((ext_vector_type(8)));
typedef _Float16 h4v __attribute__((ext_vector_type(4)));

typedef __attribute__((address_space(3))) void lds_void;
typedef const __attribute__((address_space(1))) void g_void;

__device__ __forceinline__ float b2f(bf16 x) { return __bfloat162float(x); }
__device__ __forceinline__ bf16 f2b(float x) { return __float2bfloat16(x); }

__device__ __forceinline__ unsigned short f2bs(float f) {
  bf16 h = __float2bfloat16(f);
  unsigned short s;
  __builtin_memcpy(&s, &h, 2);
  return s;
}
__device__ __forceinline__ float s2f(short s) {
  return __uint_as_float(((unsigned)(unsigned short)s) << 16);
}
__device__ __forceinline__ unsigned short h2u(_Float16 h) {
  unsigned short s;
  __builtin_memcpy(&s, &h, 2);
  return s;
}
// packed bf16-pair decode: element at lower address = low 16 bits
__device__ __forceinline__ float blo(unsigned u) { return __uint_as_float(u << 16); }
__device__ __forceinline__ float bhi(unsigned u) {
  return __uint_as_float(u & 0xffff0000u);
}

__device__ __forceinline__ void stv(float* p, float v) { *p = v; }
__device__ __forceinline__ void stv(bf16* p, float v) { *p = f2b(v); }

// ---------------------------------------------------------------------------
// Transpose + split: x [b][256][HW] f32 -> hi/lo [b][HW][256] f16.
// Extra grid slice (blockIdx.y == 4): fp32 -> (hi,lo) split of w_qkv.
// ---------------------------------------------------------------------------
__global__ __launch_bounds__(256) void transpose_split_kernel(
    const float* __restrict__ In, _Float16* __restrict__ Hi,
    _Float16* __restrict__ Lo, const float* __restrict__ W,
    _Float16* __restrict__ WHi, _Float16* __restrict__ WLo) {
  if (blockIdx.y == 4) {  // weight-conversion slice
    int id = blockIdx.z * 64 + blockIdx.x;
    if (id < 192) {
      int i = id * 256 + threadIdx.x;  // i < 49152 = 768*256/4
      f32x4 v = *(const f32x4*)(W + (size_t)i * 4);
      h4v h, l;
#pragma unroll
      for (int q = 0; q < 4; ++q) {
        _Float16 hi = (_Float16)v[q];
        h[q] = hi;
        l[q] = (_Float16)(v[q] - (float)hi);
      }
      *(h4v*)(WHi + (size_t)i * 4) = h;
      *(h4v*)(WLo + (size_t)i * 4) = l;
    }
    return;
  }
  __shared__ _Float16 sH[64][68];
  __shared__ _Float16 sL[64][68];
  const int b = blockIdx.z;
  const int n0 = blockIdx.x * 64, c0 = blockIdx.y * 64;
  const int tl = threadIdx.x & 15, tr = threadIdx.x >> 4;
  const float* Ib = In + ((size_t)b * 256 + c0) * HW + n0;
#pragma unroll
  for (int i = 0; i < 4; ++i) {
    int cc = tr + i * 16;
    f32x4 v = *(const f32x4*)(Ib + (size_t)cc * HW + tl * 4);
#pragma unroll
    for (int q = 0; q < 4; ++q) {
      _Float16 hi = (_Float16)v[q];
      sH[cc][tl * 4 + q] = hi;
      sL[cc][tl * 4 + q] = (_Float16)(v[q] - (float)hi);
    }
  }
  __syncthreads();
  size_t obase = ((size_t)b * HW + n0) * 256 + c0;
#pragma unroll
  for (int i = 0; i < 4; ++i) {
    int nn = tr + i * 16;
    h4v h, l;
#pragma unroll
    for (int q = 0; q < 4; ++q) {
      h[q] = sH[tl * 4 + q][nn];
      l[q] = sL[tl * 4 + q][nn];
    }
    *(h4v*)(Hi + obase + (size_t)nn * 256 + tl * 4) = h;
    *(h4v*)(Lo + obase + (size_t)nn * 256 + tl * 4) = l;
  }
}

// ---------------------------------------------------------------------------
// fp32 -> fp16 plain conversion for w_proj (after attn, into dead pw region).
// ---------------------------------------------------------------------------
__global__ __launch_bounds__(256) void cvt_f16_kernel(
    const float* __restrict__ W, _Float16* __restrict__ Hi, int n4) {
  int i = blockIdx.x * 256 + threadIdx.x;
  if (i >= n4) return;
  f32x4 v = *(const f32x4*)(W + (size_t)i * 4);
  h4v h;
#pragma unroll
  for (int q = 0; q < 4; ++q) h[q] = (_Float16)v[q];
  *(h4v*)(Hi + (size_t)i * 4) = h;
}

// ---------------------------------------------------------------------------
// GEMM1 dedicated kernel — r8/r11 codegen shape (measured 45.0-45.2 µs):
// 128x128 tile, 256 threads = 4 waves (2x2), 3-plane split-fp16,
// single-buffer, inline staging loops. FROZEN.
// ---------------------------------------------------------------------------
__global__ __launch_bounds__(256) void mfma_gemm1_kernel(
    const _Float16* __restrict__ A,   // [2][768][256] planes (hi, lo)
    const _Float16* __restrict__ Bt,  // [2][8][HW][256] planes (hi, lo)
    bf16* __restrict__ Out) {         // [8][768][HW]
  constexpr int M = 768, K = 256;
  __shared__ __align__(16) _Float16 sA[2][128 * 32];
  __shared__ __align__(16) _Float16 sB[2][128 * 32];
  const int b = blockIdx.z;
  const int ob = blockIdx.y * 128;
  const int nb = blockIdx.x * 128;
  const int tid = threadIdx.x;
  const int lane = tid & 63;
  const int wave = tid >> 6;
  const int wm = (wave >> 1) * 64;
  const int wn = (wave & 1) * 64;
  const int lr = lane & 15;
  const int kg = lane >> 4;

  f32x4 acc[4][4] = {};

  for (int k0 = 0; k0 < K; k0 += 32) {
#pragma unroll
    for (int p = 0; p < 2; ++p) {
      const _Float16* Ab = A + (size_t)p * M * K + (size_t)ob * K + k0;
#pragma unroll
      for (int t = 0; t < 2; ++t) {
        int c = t * 256 + tid;
        int row = c >> 2, col = c & 3;
        int kc = col ^ ((row >> 1) & 3);
        __builtin_amdgcn_global_load_lds(
            (g_void*)(Ab + (size_t)row * K + kc * 8),
            (lds_void*)(sA[p] + (size_t)(t * 256 + (tid & ~63)) * 8), 16, 0, 0);
      }
    }
#pragma unroll
    for (int q = 0; q < 2; ++q) {
      const _Float16* Bb =
          Bt + (size_t)q * 8 * HW * K + ((size_t)b * HW + nb) * K + k0;
#pragma unroll
      for (int t = 0; t < 2; ++t) {
        int c = t * 256 + tid;
        int row = c >> 2, col = c & 3;
        int kc = col ^ ((row >> 1) & 3);
        __builtin_amdgcn_global_load_lds(
            (g_void*)(Bb + (size_t)row * K + kc * 8),
            (lds_void*)(sB[q] + (size_t)(t * 256 + (tid & ~63)) * 8), 16, 0, 0);
      }
    }
    __syncthreads();

    h8v af[2][4], bf_[2][4];
#pragma unroll
    for (int p = 0; p < 2; ++p)
#pragma unroll
      for (int i = 0; i < 4; ++i) {
        int r = wm + i * 16 + lr;
        af[p][i] = *(const h8v*)(sA[p] + (size_t)r * 32 + (kg ^ ((r >> 1) & 3)) * 8);
      }
#pragma unroll
    for (int q = 0; q < 2; ++q)
#pragma unroll
      for (int j = 0; j < 4; ++j) {
        int r = wn + j * 16 + lr;
        bf_[q][j] = *(const h8v*)(sB[q] + (size_t)r * 32 + (kg ^ ((r >> 1) & 3)) * 8);
      }

#pragma unroll
    for (int i = 0; i < 4; ++i)
#pragma unroll
      for (int j = 0; j < 4; ++j) {
        acc[i][j] = __builtin_amdgcn_mfma_f32_16x16x32_f16(af[0][i], bf_[0][j],
                                                           acc[i][j], 0, 0, 0);
        acc[i][j] = __builtin_amdgcn_mfma_f32_16x16x32_f16(af[1][i], bf_[0][j],
                                                           acc[i][j], 0, 0, 0);
        acc[i][j] = __builtin_amdgcn_mfma_f32_16x16x32_f16(af[0][i], bf_[1][j],
                                                           acc[i][j], 0, 0, 0);
      }
    __syncthreads();
  }

  // epilogue: D row = (lane>>4)*4 + reg, col = lane&15  (m89-verified)
#pragma unroll
  for (int i = 0; i < 4; ++i) {
#pragma unroll
    for (int r = 0; r < 4; ++r) {
      int o = ob + wm + i * 16 + kg * 4 + r;
      bf16* orow = Out + ((size_t)b * M + o) * HW + nb + wn + lr;
#pragma unroll
      for (int j = 0; j < 4; ++j) stv(orow + j * 16, acc[i][j][r]);
    }
  }
}

// ---------------------------------------------------------------------------
// GEMM2 dedicated kernel: out = BN(w_proj @ att), consuming att in its
// NATIVE channel-major layout [b][512][HW] f16 — the transpose happens in
// LDS staging (write-side): thread holds 2 adjacent channels x 8 px,
// writes packed b32 pairs at the swizzled position kc=(c>>3)^((n>>1)&3),
// so the proven fragment-read path (kg^((r>>1)&3)) is unchanged.
// Writes <=4-way bank aliased (1.58x, 8 b32/thread/K-step). A-side keeps
// global_load_lds. Eliminates the separate 64-MiB att transpose pass.
// ---------------------------------------------------------------------------
__global__ __launch_bounds__(256) void mfma_gemm2_kernel(
    const _Float16* __restrict__ A,    // [256][512] w_proj f16
    const _Float16* __restrict__ att,  // [8][512][HW] f16 (channel-major)
    float* __restrict__ Out,           // [8][256][HW]
    const float* __restrict__ bng, const float* __restrict__ bnb,
    const float* __restrict__ bnm, const float* __restrict__ bnv) {
  constexpr int M = 256, K = 512;
  __shared__ __align__(16) _Float16 sA[64 * 32];
  __shared__ __align__(16) _Float16 sB[128 * 32];
  const int b = blockIdx.z;
  const int ob = blockIdx.y * 64;
  const int nb = blockIdx.x * 128;
  const int tid = threadIdx.x;
  const int lane = tid & 63;
  const int wave = tid >> 6;
  const int wm = (wave >> 1) * 32;
  const int wn = (wave & 1) * 64;
  const int lr = lane & 15;
  const int kg = lane >> 4;
  // B-staging mapping: thread owns channels (c2, c2+1) x 8 pixels
  const int c2 = (tid & 15) * 2;
  const int ng = tid >> 4;  // 0..15, 8 px each -> 128 n total
  const _Float16* att_b = att + (size_t)b * 512 * HW + nb + ng * 8;

  f32x4 acc[2][4] = {};

  for (int k0 = 0; k0 < K; k0 += 32) {
    {  // ---- A stage: 64 rows x 32 k, 1 global_load_lds per thread ----
      int row = tid >> 2, col = tid & 3;
      int kc = col ^ ((row >> 1) & 3);
      __builtin_amdgcn_global_load_lds(
          (g_void*)(A + (size_t)(ob + row) * K + k0 + kc * 8),
          (lds_void*)(sA + (size_t)(tid & ~63) * 8), 16, 0, 0);
    }
    // ---- B stage: coalesced f16 reads along n, transposed+swizzled LDS ----
    h8v va = *(const h8v*)(att_b + (size_t)(k0 + c2) * HW);
    h8v vb = *(const h8v*)(att_b + (size_t)(k0 + c2 + 1) * HW);
#pragma unroll
    for (int i = 0; i < 8; ++i) {
      int n = ng * 8 + i;
      int kc = (c2 >> 3) ^ ((n >> 1) & 3);
      unsigned u = ((unsigned)h2u(vb[i]) << 16) | (unsigned)h2u(va[i]);
      *(unsigned*)(sB + n * 32 + kc * 8 + (c2 & 7)) = u;
    }
    __syncthreads();  // drains vmcnt (A) + lgkm (B writes)

    h8v af[2], bf_[4];
#pragma unroll
    for (int i = 0; i < 2; ++i) {
      int r = wm + i * 16 + lr;
      af[i] = *(const h8v*)(sA + (size_t)r * 32 + (kg ^ ((r >> 1) & 3)) * 8);
    }
#pragma unroll
    for (int j = 0; j < 4; ++j) {
      int r = wn + j * 16 + lr;
      bf_[j] = *(const h8v*)(sB + (size_t)r * 32 + (kg ^ ((r >> 1) & 3)) * 8);
    }
#pragma unroll
    for (int i = 0; i < 2; ++i)
#pragma unroll
      for (int j = 0; j < 4; ++j)
        acc[i][j] = __builtin_amdgcn_mfma_f32_16x16x32_f16(af[i], bf_[j],
                                                           acc[i][j], 0, 0, 0);
    __syncthreads();
  }

  // epilogue: BN fused; D row = (lane>>4)*4 + reg, col = lane&15
#pragma unroll
  for (int i = 0; i < 2; ++i) {
#pragma unroll
    for (int r = 0; r < 4; ++r) {
      int o = ob + wm + i * 16 + kg * 4 + r;
      float scale = bng[o] * rsqrtf(bnv[o] + 1e-5f);
      float shift = bnb[o] - bnm[o] * scale;
      float* orow = Out + ((size_t)b * M + o) * HW + nb + wn + lr;
#pragma unroll
      for (int j = 0; j < 4; ++j) orow[j * 16] = acc[i][j][r] * scale + shift;
    }
  }
}

// ---------------------------------------------------------------------------
// Fused depthwise 5x5 + grouped pointwise — bf16 LDS tile. (unchanged)
// ---------------------------------------------------------------------------
__global__ __launch_bounds__(256) void dwpw_kernel(
    const bf16* __restrict__ qkv,   // [B, 768, HW]
    const float* __restrict__ wdw,  // [768, 25]
    const float* __restrict__ wpw,  // [96, 8, 8]
    bf16* __restrict__ pw) {        // [B, 768, HW]
  constexpr int PLANE = 1484;
  constexpr int ROW = 72;
  __shared__ __align__(16) short sQ[8 * PLANE];
  const int b = blockIdx.z;
  const int g = blockIdx.y;
  const int h0 = blockIdx.x * 16;
  const int tid = threadIdx.x;
  const bf16* qb = qkv + ((size_t)b * 768 + g * 8) * HW;

  if (tid < 160) {
    int ci = tid / 20, rr = tid % 20;
    *(int*)&sQ[ci * PLANE + rr * ROW + 0] = 0;
    *(int*)&sQ[ci * PLANE + rr * ROW + 66] = 0;
  }

#pragma unroll
  for (int i = 0; i < 5; ++i) {
    int slot = tid + i * 256;
    int ci = slot & 7;
    int seg = (slot >> 3) & 7;
    int rr = slot >> 6;
    int h = h0 + rr - 2;
    int w4[4] = {0, 0, 0, 0};
    if (h >= 0 && h < 64) {
      s8v raw = *(const s8v*)(qb + (size_t)ci * HW + h * 64 + seg * 8);
      __builtin_memcpy(w4, &raw, 16);
    }
    short* dst = &sQ[ci * PLANE + rr * ROW + 2 + seg * 8];
#pragma unroll
    for (int q = 0; q < 4; ++q) ((int*)dst)[q] = w4[q];
  }
  __syncthreads();

  const int r = tid >> 4;
  const int c4 = (tid & 15) * 4;

  float accdw[8][4] = {};
#pragma unroll
  for (int ci = 0; ci < 8; ++ci) {
    const short* rowb = &sQ[ci * PLANE + r * ROW + c4];
#pragma unroll
    for (int dy = 0; dy < 5; ++dy) {
      uint2 ua = *(const uint2*)(rowb + dy * ROW);
      uint2 ub = *(const uint2*)(rowb + dy * ROW + 4);
      float win[8] = {blo(ua.x), bhi(ua.x), blo(ua.y), bhi(ua.y),
                      blo(ub.x), bhi(ub.x), blo(ub.y), bhi(ub.y)};
#pragma unroll
      for (int dx = 0; dx < 5; ++dx) {
        float wv = wdw[(g * 8 + ci) * 25 + dy * 5 + dx];
#pragma unroll
        for (int j = 0; j < 4; ++j)
          accdw[ci][j] = fmaf(wv, win[j + dx], accdw[ci][j]);
      }
    }
  }

  bf16* obase = pw + ((size_t)b * 768 + g * 8) * HW + (h0 + r) * 64 + c4;
#pragma unroll
  for (int o = 0; o < 8; ++o) {
    float a[4] = {};
#pragma unroll
    for (int i = 0; i < 8; ++i) {
      float wv = wpw[g * 64 + o * 8 + i];
#pragma unroll
      for (int j = 0; j < 4; ++j) a[j] = fmaf(wv, accdw[i][j], a[j]);
    }
    s4v res;
#pragma unroll
    for (int j = 0; j < 4; ++j) res[j] = (short)f2bs(a[j]);
    *(s4v*)(obase + (size_t)o * HW) = res;
  }
}

// ---------------------------------------------------------------------------
// ReLU linear attention — r11 structure (MFMA kv, block-per-(b,head),
// coalesced channel-major stores), output dtype f16 (GEMM2 consumes it
// natively; f16 rounding is tighter than bf16).
// ---------------------------------------------------------------------------
__global__ __launch_bounds__(256) void attn_kernel(
    const bf16* __restrict__ qkv,   // [B, 768, HW]
    const bf16* __restrict__ pw,    // [B, 768, HW]
    _Float16* __restrict__ att) {   // [B, 512, HW] f16 channel-major
  const int bh = blockIdx.x;
  const int b = bh >> 6, h = bh & 63;
  const bf16* src = (h < 32) ? qkv + ((size_t)b * 768 + 24 * h) * HW
                             : pw + ((size_t)b * 768 + 24 * h - 768) * HW;
  const int tid = threadIdx.x;
  const int lane = tid & 63, wave = tid >> 6;
  const int fr = lane & 15;  // A-row / B-col index
  const int kg = lane >> 4;  // k-slot group (8 px each)

  const bf16* Kbase = src + (size_t)8 * HW;
  const bf16* Vbase = src + (size_t)16 * HW;
  const bool isK = fr < 8;

  s8v ones;
#pragma unroll
  for (int q = 0; q < 8; ++q) ones[q] = (short)0x3F80;  // bf16 1.0

  f32x4 acc[4] = {};
#pragma unroll
  for (int step = 0; step < 32; ++step) {
    const int px = wave * 1024 + step * 32 + kg * 8;
    s8v a = {};
    s8v bv = {};
    if (isK) {
      a = *(const s8v*)(Kbase + (size_t)fr * HW + px);
      unsigned au[4];
      __builtin_memcpy(au, &a, 16);
#pragma unroll
      for (int q = 0; q < 4; ++q) {
        unsigned s = (au[q] & 0x80008000u) >> 15;
        au[q] &= ~((s << 16) - s);
      }
      __builtin_memcpy(&a, au, 16);
      bv = *(const s8v*)(Vbase + (size_t)fr * HW + px);
    } else if (fr == 8) {
      bv = ones;
    }
    acc[step & 3] =
        __builtin_amdgcn_mfma_f32_16x16x32_bf16(a, bv, acc[step & 3], 0, 0, 0);
  }
  f32x4 accs = (acc[0] + acc[1]) + (acc[2] + acc[3]);

  __shared__ float sAcc[4][64][4];
  __shared__ float sKV[72];
#pragma unroll
  for (int q = 0; q < 4; ++q) sAcc[wave][lane][q] = accs[q];
  __syncthreads();
  if (wave == 0) {
#pragma unroll
    for (int q = 0; q < 4; ++q) {
      int r = kg * 4 + q;  // C row = d
      if (r < 8 && fr < 9) {
        sKV[r * 9 + fr] = sAcc[0][lane][q] + sAcc[1][lane][q] +
                          sAcc[2][lane][q] + sAcc[3][lane][q];
      }
    }
  }
  __syncthreads();
  float kvf[72];
#pragma unroll
  for (int t = 0; t < 72; ++t) kvf[t] = sKV[t];

  // q-pass: out = (q . kv) normalized; 16 px/thread, h8v f16 stores
  _Float16* obase = att + ((size_t)b * 512 + h * 8) * HW;
  for (int n0 = tid * 8; n0 < HW; n0 += 2048) {
    s8v qvec[8];
#pragma unroll
    for (int d = 0; d < 8; ++d)
      qvec[d] = *(const s8v*)(src + (size_t)d * HW + n0);
    h8v res[8];
#pragma unroll
    for (int p = 0; p < 8; ++p) {
      float qd[8];
#pragma unroll
      for (int d = 0; d < 8; ++d) qd[d] = fmaxf(s2f(qvec[d][p]), 0.f);
      float o[9] = {};
#pragma unroll
      for (int d = 0; d < 8; ++d)
#pragma unroll
        for (int e = 0; e < 9; ++e) o[e] = fmaf(qd[d], kvf[d * 9 + e], o[e]);
      float rinv = 1.0f / (o[8] + 1e-15f);
#pragma unroll
      for (int e = 0; e < 8; ++e) res[e][p] = (_Float16)(o[e] * rinv);
    }
#pragma unroll
    for (int e = 0; e < 8; ++e)
      *(h8v*)(obase + (size_t)e * HW + n0) = res[e];
  }
}

// ---------------------------------------------------------------------------
extern "C" void kernel_launch(void* const* d_in, const int* in_sizes, int n_in,
                              void* d_out, int out_size, void* d_ws, size_t ws_size,
                              hipStream_t stream) {
  const float* x = (const float*)d_in[0];       // [8,256,64,64]
  const float* w_qkv = (const float*)d_in[1];   // [768,256]
  const float* w_dw = (const float*)d_in[2];    // [768,1,5,5]
  const float* w_pw = (const float*)d_in[3];    // [96,8,8]
  const float* w_proj = (const float*)d_in[4];  // [256,512]
  const float* bng = (const float*)d_in[5];
  const float* bnb = (const float*)d_in[6];
  const float* bnm = (const float*)d_in[7];
  const float* bnv = (const float*)d_in[8];
  float* out = (float*)d_out;  // [8,256,64,64]

  // Workspace: 128 MiB, aliased by liveness.
  bf16* qkv = (bf16*)d_ws;                       // [8][768][HW]  48 MiB
  bf16* pw = qkv + (size_t)8 * 768 * HW;         // [8][768][HW]  48 MiB
  bf16* attreg = pw + (size_t)8 * 768 * HW;      // 32 MiB scratch region

  _Float16* xt_hi = (_Float16*)attreg;           // [8][HW][256] (dead after GEMM1)
  _Float16* xt_lo = xt_hi + (size_t)8 * HW * 256;
  _Float16* wq_hi = (_Float16*)pw;               // [768][256] x2 (pw dead until dwpw)
  _Float16* wq_lo = wq_hi + (size_t)768 * 256;
  _Float16* att_f = (_Float16*)attreg;           // [8][512][HW] f16 = 32 MiB exactly
                                                 //  (xt planes dead at attn time)
  _Float16* wp_hi = (_Float16*)pw;               // [256][512] (pw dead after attn)

  // 0) transpose+split x; fused slice also split-converts w_qkv
  transpose_split_kernel<<<dim3(64, 5, 8), 256, 0, stream>>>(
      x, xt_hi, xt_lo, w_qkv, wq_hi, wq_lo);

  // 1) qkv = w_qkv @ x  (M=768, K=256) — r11 128x128 inline kernel
  //    (3 planes REQUIRED: relu-boundary sign sensitivity in attention)
  mfma_gemm1_kernel<<<dim3(32, 6, 8), 256, 0, stream>>>(wq_hi, xt_hi, qkv);

  // 2) pw = grouped_pointwise(depthwise5x5(qkv))   (overwrites wq planes — dead)
  dwpw_kernel<<<dim3(4, 96, 8), 256, 0, stream>>>(qkv, w_dw, w_pw, pw);

  // 3) att = relu_linear_attention(concat(qkv, pw)) — f16 channel-major
  //    output, coalesced stores (overwrites xt planes — dead)
  attn_kernel<<<dim3(512), 256, 0, stream>>>(qkv, pw, att_f);

  // 4) fp16-convert w_proj into dead pw region
  cvt_f16_kernel<<<dim3(128), 256, 0, stream>>>(w_proj, wp_hi, 256 * 512 / 4);

  // 5) out = BN(w_proj @ att) — consumes att channel-major directly
  //    (LDS write-side transpose); no separate transpose pass
  mfma_gemm2_kernel<<<dim3(32, 4, 8), 256, 0, stream>>>(wp_hi, att_f, out, bng,
                                                        bnb, bnm, bnv);
}